// Round 7
// baseline (512.352 us; speedup 1.0000x reference)
//
#include <hip/hip_runtime.h>
#include <hip/hip_cooperative_groups.h>
#include <hip/hip_fp16.h>
#include <math.h>

namespace cg = cooperative_groups;

#define D 1024
#define NROWS 16384
#define NBUF 512
#define NBLK 1024

// unified ws layout (float indices) — shared by fused and fallback paths
#define OFF_STAT 0      // 4096 floats: ax|bx|ay|by (fallback k_init)
#define OFF_AX   0
#define OFF_BX   1024
#define OFF_AY   2048
#define OFF_BY   3072
#define OFF_MEAN 4096   // 1024 floats: column sums of y1
#define OFF_KEY  5120   // unsigned long long (byte 20480, 8-aligned)
#define OFF_CONST 5124  // tau_in, tau_out, a_in, a_out (fallback)
#define OFF_GATE 5632   // 16384 floats
#define OFF_PART 22016  // NP x 1024 floats

typedef float nfloat4 __attribute__((ext_vector_type(4)));

__device__ __forceinline__ float4 ld4(const float* p) { return *(const float4*)p; }
__device__ __forceinline__ void st4_nt(float* p, float4 v) {
    nfloat4 nv = { v.x, v.y, v.z, v.w };
    __builtin_nontemporal_store(nv, (nfloat4*)p);
}

__device__ __forceinline__ float wave_red(float v) {
    #pragma unroll
    for (int off = 32; off > 0; off >>= 1) v += __shfl_xor(v, off, 64);
    return v;
}

__device__ __forceinline__ float gelu_f(float x) {
    float x2 = x * x;
    float t1 = fmaf(0.044715f, x2, 1.0f);
    float u2 = (1.5957691216057308f * x) * t1;
    float e  = __expf(u2);
    float r  = __builtin_amdgcn_rcpf(e + 1.0f);
    return fmaf(-x, r, x);
}

__device__ __forceinline__ float4 gelu4(float4 x) {
    float4 y;
    y.x = gelu_f(x.x); y.y = gelu_f(x.y); y.z = gelu_f(x.z); y.w = gelu_f(x.w);
    return y;
}

__device__ __forceinline__ float2 uh2f(unsigned int u) {
    __half2 h;
    __builtin_memcpy(&h, &u, 4);
    return __half22float2(h);
}

__device__ __forceinline__ unsigned int packh2(float a, float b) {
    __half2 h = __floats2half2_rn(a, b);
    unsigned int u;
    __builtin_memcpy(&u, &h, 4);
    return u;
}

// ======================= FUSED cooperative kernel ============================
// LDS: s_mem[2048] uints = 8 KB. Phase A loop: [0..1023]=x-stats(h2 a,b),
// [1024..2047]=y-stats. After loop: [0..1023] floats = acc / v; [1024..1039]
// floats = s_red/s_sc scratch.
__global__ __launch_bounds__(256, 4) void k_fused(
        const float* __restrict__ x,
        const float* __restrict__ ema_x,  const float* __restrict__ ema_x2,
        const float* __restrict__ ema_y,  const float* __restrict__ ema_y2,
        const float* __restrict__ lti,    const float* __restrict__ lto,
        const float* __restrict__ lai,    const float* __restrict__ lao,
        const float* __restrict__ buf,    const float* __restrict__ facil,
        const float* __restrict__ lkb,    const float* __restrict__ lkd,
        const unsigned char* __restrict__ mask,
        float* __restrict__ ws,           float* __restrict__ out) {
    cg::grid_group grid = cg::this_grid();
    __shared__ unsigned int s_mem[2048];
    float* s_f   = (float*)s_mem;            // acc (phase A tail) / v (phase D)
    float* s_red = (float*)&s_mem[1024];     // 4 floats
    float* s_sc  = (float*)&s_mem[1032];     // 4 floats
    const int tid = threadIdx.x, wave = tid >> 6, lane = tid & 63;
    const int b = blockIdx.x;

    // ---- phase A prologue: fold stats into fp16 pairs in LDS ----
    for (int i = tid; i < 1024; i += 256) {
        float mx = ema_x[i];
        float vx = fmaxf(ema_x2[i] - mx * mx, 0.0f);
        float ax = 1.0f / (sqrtf(vx) + 1e-5f);
        s_mem[i] = packh2(ax, mx * ax);
        float my = ema_y[i];
        float vy = fmaxf(ema_y2[i] - my * my, 0.0f);
        float ay = 1.0f / (sqrtf(vy) + 1e-5f);
        s_mem[1024 + i] = packh2(ay, my * ay);
    }
    if (b == 0 && tid == 0) *(unsigned long long*)&ws[OFF_KEY] = 0ull;
    __syncthreads();

    const float tau_in = __expf(lti[0]), tau_out = __expf(lto[0]);
    const float a_in  = 1.0f / (1.0f + __expf(-lai[0]));
    const float a_out = 1.0f / (1.0f + __expf(-lao[0]));

    int col[4];
    #pragma unroll
    for (int j = 0; j < 4; ++j) col[j] = 4 * lane + 256 * j;

    float4 acc[4];
    #pragma unroll
    for (int j = 0; j < 4; ++j) acc[j] = make_float4(0.f, 0.f, 0.f, 0.f);

    const int r0 = (b * 4 + wave) * 4;   // 4 rows/wave, 16 rows/block

    // ---- phase A: 2 rows at a time (2x memory parallelism) ----
    #pragma unroll
    for (int k = 0; k < 2; ++k) {
        const int rA = r0 + 2 * k, rB = rA + 1;
        const float* pA = x + (size_t)rA * D;
        const float* pB = x + (size_t)rB * D;
        float4 xA[4], xB[4];
        #pragma unroll
        for (int j = 0; j < 4; ++j) { xA[j] = ld4(&pA[col[j]]); xB[j] = ld4(&pB[col[j]]); }
        float4 yA[4], yB[4];
        float zinA = 0.f, zoutA = 0.f, zinB = 0.f, zoutB = 0.f;
        #pragma unroll
        for (int j = 0; j < 4; ++j) {
            uint4 ux = *(const uint4*)&s_mem[col[j]];
            uint4 uy = *(const uint4*)&s_mem[1024 + col[j]];
            float2 s0 = uh2f(ux.x), s1 = uh2f(ux.y), s2 = uh2f(ux.z), s3 = uh2f(ux.w);
            float d;
            d = fmaf(xA[j].x, s0.x, -s0.y); zinA = fmaf(d, d, zinA);
            d = fmaf(xA[j].y, s1.x, -s1.y); zinA = fmaf(d, d, zinA);
            d = fmaf(xA[j].z, s2.x, -s2.y); zinA = fmaf(d, d, zinA);
            d = fmaf(xA[j].w, s3.x, -s3.y); zinA = fmaf(d, d, zinA);
            d = fmaf(xB[j].x, s0.x, -s0.y); zinB = fmaf(d, d, zinB);
            d = fmaf(xB[j].y, s1.x, -s1.y); zinB = fmaf(d, d, zinB);
            d = fmaf(xB[j].z, s2.x, -s2.y); zinB = fmaf(d, d, zinB);
            d = fmaf(xB[j].w, s3.x, -s3.y); zinB = fmaf(d, d, zinB);
            yA[j] = gelu4(xA[j]);
            yB[j] = gelu4(xB[j]);
            float2 t0 = uh2f(uy.x), t1 = uh2f(uy.y), t2 = uh2f(uy.z), t3 = uh2f(uy.w);
            d = fmaf(yA[j].x, t0.x, -t0.y); zoutA = fmaf(d, d, zoutA);
            d = fmaf(yA[j].y, t1.x, -t1.y); zoutA = fmaf(d, d, zoutA);
            d = fmaf(yA[j].z, t2.x, -t2.y); zoutA = fmaf(d, d, zoutA);
            d = fmaf(yA[j].w, t3.x, -t3.y); zoutA = fmaf(d, d, zoutA);
            d = fmaf(yB[j].x, t0.x, -t0.y); zoutB = fmaf(d, d, zoutB);
            d = fmaf(yB[j].y, t1.x, -t1.y); zoutB = fmaf(d, d, zoutB);
            d = fmaf(yB[j].z, t2.x, -t2.y); zoutB = fmaf(d, d, zoutB);
            d = fmaf(yB[j].w, t3.x, -t3.y); zoutB = fmaf(d, d, zoutB);
        }
        zinA  = wave_red(zinA)  * (1.0f / D);
        zinB  = wave_red(zinB)  * (1.0f / D);
        zoutA = wave_red(zoutA) * (1.0f / D);
        zoutB = wave_red(zoutB) * (1.0f / D);
        float gA = ((1.0f - a_in)  + a_in  * __expf(-tau_in  * zinA)) *
                   ((1.0f - a_out) + a_out * __expf(-tau_out * zoutA));
        float gB = ((1.0f - a_in)  + a_in  * __expf(-tau_in  * zinB)) *
                   ((1.0f - a_out) + a_out * __expf(-tau_out * zoutB));
        if (lane == 0) { ws[OFF_GATE + rA] = gA; ws[OFF_GATE + rB] = gB; }
        #pragma unroll
        for (int j = 0; j < 4; ++j) {
            acc[j].x = fmaf(yA[j].x, gA, fmaf(yB[j].x, gB, acc[j].x));
            acc[j].y = fmaf(yA[j].y, gA, fmaf(yB[j].y, gB, acc[j].y));
            acc[j].z = fmaf(yA[j].z, gA, fmaf(yB[j].z, gB, acc[j].z));
            acc[j].w = fmaf(yA[j].w, gA, fmaf(yB[j].w, gB, acc[j].w));
        }
    }
    __syncthreads();                       // stats now dead; reuse LDS as acc
    for (int i = tid; i < 1024; i += 256) s_f[i] = 0.0f;
    __syncthreads();
    #pragma unroll
    for (int j = 0; j < 4; ++j) {
        atomicAdd(&s_f[col[j] + 0], acc[j].x);
        atomicAdd(&s_f[col[j] + 1], acc[j].y);
        atomicAdd(&s_f[col[j] + 2], acc[j].z);
        atomicAdd(&s_f[col[j] + 3], acc[j].w);
    }
    __syncthreads();
    *(float4*)&ws[OFF_PART + (size_t)b * D + 4 * tid] = *(float4*)&s_f[4 * tid];

    grid.sync();

    // ---- phase B: deterministic partial reduction -> column sums ----
    if (b < 64) {
        const int g = b * 4 + wave;        // column group 0..255 (4 cols)
        float4 s = make_float4(0.f, 0.f, 0.f, 0.f);
        for (int rr = lane; rr < NBLK; rr += 64) {
            float4 p = ld4(&ws[OFF_PART + (size_t)rr * D + 4 * g]);
            s.x += p.x; s.y += p.y; s.z += p.z; s.w += p.w;
        }
        s.x = wave_red(s.x); s.y = wave_red(s.y);
        s.z = wave_red(s.z); s.w = wave_red(s.w);
        if (lane == 0) *(float4*)&ws[OFF_MEAN + 4 * g] = s;
    }

    grid.sync();

    // ---- phase C: sims over buf + argmax ----
    if (b < 128) {
        float4 mv = ld4(&ws[OFF_MEAN + 4 * tid]);
        float ns = mv.x * mv.x + mv.y * mv.y + mv.z * mv.z + mv.w * mv.w;
        ns = wave_red(ns);
        if (lane == 0) s_red[wave] = ns;
        __syncthreads();
        if (tid == 0) {
            float t = s_red[0] + s_red[1] + s_red[2] + s_red[3];
            s_sc[0] = 1.0f / fmaxf(sqrtf(t), 1e-12f);
        }
        __syncthreads();
        const float inv = s_sc[0];
        float4 mvv[4];
        #pragma unroll
        for (int j = 0; j < 4; ++j) mvv[j] = ld4(&ws[OFF_MEAN + col[j]]);
        const int n = b * 4 + wave;        // 512 buf rows, 1/wave
        const float* br = buf + (size_t)n * D;
        float dot = 0.f, bns = 0.f;
        #pragma unroll
        for (int j = 0; j < 4; ++j) {
            float4 bv = ld4(&br[col[j]]);
            dot = fmaf(bv.x, mvv[j].x, dot); dot = fmaf(bv.y, mvv[j].y, dot);
            dot = fmaf(bv.z, mvv[j].z, dot); dot = fmaf(bv.w, mvv[j].w, dot);
            bns = fmaf(bv.x, bv.x, bns); bns = fmaf(bv.y, bv.y, bns);
            bns = fmaf(bv.z, bv.z, bns); bns = fmaf(bv.w, bv.w, bns);
        }
        dot = wave_red(dot);
        bns = wave_red(bns);
        if (lane == 0) {
            float sim = -1.0f;
            if (mask[n]) sim = (dot * inv) / fmaxf(sqrtf(bns), 1e-12f);
            unsigned int fb = __float_as_uint(sim);
            unsigned int mono = (fb & 0x80000000u) ? ~fb : (fb | 0x80000000u);
            unsigned long long key = ((unsigned long long)mono << 32) | (unsigned int)(~n);
            atomicMax((unsigned long long*)&ws[OFF_KEY], key);
        }
    }

    grid.sync();

    // ---- phase D: decode winner, project same 16 rows, write out ----
    const unsigned long long key = *(volatile unsigned long long*)&ws[OFF_KEY];
    const int idx = (int)(~(unsigned int)(key & 0xFFFFFFFFull));
    const unsigned int mono = (unsigned int)(key >> 32);
    const unsigned int fbv = (mono & 0x80000000u) ? (mono ^ 0x80000000u) : ~mono;
    const float sim = __uint_as_float(fbv);

    float4 vt = ld4(&buf[(size_t)idx * D + 4 * tid]);
    float bns2 = 0.f;
    if (!isfinite(vt.x) || !isfinite(vt.y) || !isfinite(vt.z) || !isfinite(vt.w))
        bns2 = __uint_as_float(0x7FC00000u);   // NaN poison -> valid=0
    bns2 += vt.x * vt.x + vt.y * vt.y + vt.z * vt.z + vt.w * vt.w;
    bns2 = wave_red(bns2);
    if (lane == 0) s_red[wave] = bns2;
    __syncthreads();
    if (tid == 0) {
        float t = s_red[0] + s_red[1] + s_red[2] + s_red[3];
        int valid = (t >= 1e-12f) ? 1 : 0;     // NaN compares false
        float sim_val = fminf(fmaxf(sim, 0.0f), 1.0f);
        float fl = facil[idx] * ((sim_val > 0.88f) ? 2.0f : 1.0f);
        float mod = (fl - 1.0f) * sim_val;
        float kb = fminf(fmaxf(__expf(lkb[0]), 0.01f), 4.0f);
        float kd = fminf(fmaxf(__expf(lkd[0]), 0.01f), 0.9f);
        float boost = 1.0f + kb * mod;
        float damp = fmaxf(0.01f, 1.0f - kd * mod);
        s_sc[0] = valid ? damp : 1.0f;
        s_sc[1] = valid ? (boost - damp) : 0.0f;
        s_sc[2] = (float)valid;
    }
    __syncthreads();
    const float dampe = s_sc[0], coef = s_sc[1];
    if (s_sc[2] == 0.0f) vt = make_float4(0.f, 0.f, 0.f, 0.f);
    __syncthreads();
    *(float4*)&s_f[4 * tid] = vt;              // v into LDS
    __syncthreads();

    float4 vv[4];
    #pragma unroll
    for (int j = 0; j < 4; ++j) vv[j] = *(const float4*)&s_f[col[j]];

    #pragma unroll
    for (int k = 0; k < 2; ++k) {
        const int rA = r0 + 2 * k, rB = rA + 1;
        const float gA = ws[OFF_GATE + rA], gB = ws[OFF_GATE + rB];
        const float* pA = x + (size_t)rA * D;
        const float* pB = x + (size_t)rB * D;
        float4 xA[4], xB[4];
        #pragma unroll
        for (int j = 0; j < 4; ++j) { xA[j] = ld4(&pA[col[j]]); xB[j] = ld4(&pB[col[j]]); }
        float4 yA[4], yB[4];
        float projA = 0.f, projB = 0.f;
        #pragma unroll
        for (int j = 0; j < 4; ++j) {
            yA[j] = gelu4(xA[j]);
            yA[j].x *= gA; yA[j].y *= gA; yA[j].z *= gA; yA[j].w *= gA;
            yB[j] = gelu4(xB[j]);
            yB[j].x *= gB; yB[j].y *= gB; yB[j].z *= gB; yB[j].w *= gB;
            projA = fmaf(yA[j].x, vv[j].x, projA); projA = fmaf(yA[j].y, vv[j].y, projA);
            projA = fmaf(yA[j].z, vv[j].z, projA); projA = fmaf(yA[j].w, vv[j].w, projA);
            projB = fmaf(yB[j].x, vv[j].x, projB); projB = fmaf(yB[j].y, vv[j].y, projB);
            projB = fmaf(yB[j].z, vv[j].z, projB); projB = fmaf(yB[j].w, vv[j].w, projB);
        }
        projA = wave_red(projA);
        projB = wave_red(projB);
        const float pcA = projA * coef, pcB = projB * coef;
        float* oA = out + (size_t)rA * D;
        float* oB = out + (size_t)rB * D;
        #pragma unroll
        for (int j = 0; j < 4; ++j) {
            float4 o;
            o.x = fmaf(yA[j].x, dampe, pcA * vv[j].x);
            o.y = fmaf(yA[j].y, dampe, pcA * vv[j].y);
            o.z = fmaf(yA[j].z, dampe, pcA * vv[j].z);
            o.w = fmaf(yA[j].w, dampe, pcA * vv[j].w);
            st4_nt(&oA[col[j]], o);
            o.x = fmaf(yB[j].x, dampe, pcB * vv[j].x);
            o.y = fmaf(yB[j].y, dampe, pcB * vv[j].y);
            o.z = fmaf(yB[j].z, dampe, pcB * vv[j].z);
            o.w = fmaf(yB[j].w, dampe, pcB * vv[j].w);
            st4_nt(&oB[col[j]], o);
        }
    }
}

// ======================= FALLBACK path (verified R5 kernels) =================
__device__ __forceinline__ float4 inv_std4(float4 m, float4 m2) {
    float4 r;
    r.x = 1.0f / (sqrtf(fmaxf(m2.x - m.x * m.x, 0.f)) + 1e-5f);
    r.y = 1.0f / (sqrtf(fmaxf(m2.y - m.y * m.y, 0.f)) + 1e-5f);
    r.z = 1.0f / (sqrtf(fmaxf(m2.z - m.z * m.z, 0.f)) + 1e-5f);
    r.w = 1.0f / (sqrtf(fmaxf(m2.w - m.w * m.w, 0.f)) + 1e-5f);
    return r;
}

__global__ void k_init(const float* __restrict__ ema_x, const float* __restrict__ ema_x2,
                       const float* __restrict__ ema_y, const float* __restrict__ ema_y2,
                       const float* __restrict__ lti, const float* __restrict__ lto,
                       const float* __restrict__ lai, const float* __restrict__ lao,
                       float* __restrict__ ws) {
    int t = threadIdx.x;
    if (t < D) {
        float mx = ema_x[t];
        float vx = fmaxf(ema_x2[t] - mx * mx, 0.0f);
        float ax = 1.0f / (sqrtf(vx) + 1e-5f);
        ws[OFF_AX + t] = ax;
        ws[OFF_BX + t] = mx * ax;
        float my = ema_y[t];
        float vy = fmaxf(ema_y2[t] - my * my, 0.0f);
        float ay = 1.0f / (sqrtf(vy) + 1e-5f);
        ws[OFF_AY + t] = ay;
        ws[OFF_BY + t] = my * ay;
        ws[OFF_MEAN + t] = 0.0f;
    }
    if (t == 0) {
        *(unsigned long long*)&ws[OFF_KEY] = 0ull;
        ws[OFF_CONST + 0] = __expf(lti[0]);
        ws[OFF_CONST + 1] = __expf(lto[0]);
        ws[OFF_CONST + 2] = 1.0f / (1.0f + __expf(-lai[0]));
        ws[OFF_CONST + 3] = 1.0f / (1.0f + __expf(-lao[0]));
    }
}

template<int RPW>
__global__ __launch_bounds__(256, 4) void k_passA(const float* __restrict__ x,
                                                  float* __restrict__ ws) {
    __shared__ float s_stat[4096];
    __shared__ float s_acc[D];
    const int tid = threadIdx.x;
    const int wave = tid >> 6, lane = tid & 63;
    for (int i = tid; i < 1024; i += 256) {
        *(float4*)&s_stat[4 * i] = ld4(&ws[OFF_STAT + 4 * i]);
        s_acc[i] = 0.0f;
    }
    __syncthreads();
    const float tau_in = ws[OFF_CONST + 0], tau_out = ws[OFF_CONST + 1];
    const float a_in  = ws[OFF_CONST + 2], a_out  = ws[OFF_CONST + 3];
    int col[4];
    #pragma unroll
    for (int j = 0; j < 4; ++j) col[j] = 4 * lane + 256 * j;
    float4 acc[4];
    #pragma unroll
    for (int j = 0; j < 4; ++j) acc[j] = make_float4(0.f, 0.f, 0.f, 0.f);
    const int r0 = (blockIdx.x * 4 + wave) * RPW;
    for (int r = r0; r < r0 + RPW; ++r) {
        const float* xr = x + (size_t)r * D;
        float4 xv[4];
        #pragma unroll
        for (int j = 0; j < 4; ++j) xv[j] = ld4(&xr[col[j]]);
        float4 yv[4];
        float zin = 0.f, zout = 0.f;
        #pragma unroll
        for (int j = 0; j < 4; ++j) {
            float4 a = *(const float4*)&s_stat[OFF_AX + col[j]];
            float4 b = *(const float4*)&s_stat[OFF_BX + col[j]];
            float dx;
            dx = fmaf(xv[j].x, a.x, -b.x); zin = fmaf(dx, dx, zin);
            dx = fmaf(xv[j].y, a.y, -b.y); zin = fmaf(dx, dx, zin);
            dx = fmaf(xv[j].z, a.z, -b.z); zin = fmaf(dx, dx, zin);
            dx = fmaf(xv[j].w, a.w, -b.w); zin = fmaf(dx, dx, zin);
            yv[j] = gelu4(xv[j]);
            float4 ay = *(const float4*)&s_stat[OFF_AY + col[j]];
            float4 by = *(const float4*)&s_stat[OFF_BY + col[j]];
            float dy;
            dy = fmaf(yv[j].x, ay.x, -by.x); zout = fmaf(dy, dy, zout);
            dy = fmaf(yv[j].y, ay.y, -by.y); zout = fmaf(dy, dy, zout);
            dy = fmaf(yv[j].z, ay.z, -by.z); zout = fmaf(dy, dy, zout);
            dy = fmaf(yv[j].w, ay.w, -by.w); zout = fmaf(dy, dy, zout);
        }
        zin  = wave_red(zin)  * (1.0f / D);
        zout = wave_red(zout) * (1.0f / D);
        float g = ((1.0f - a_in)  + a_in  * __expf(-tau_in  * zin)) *
                  ((1.0f - a_out) + a_out * __expf(-tau_out * zout));
        if (lane == 0) ws[OFF_GATE + r] = g;
        #pragma unroll
        for (int j = 0; j < 4; ++j) {
            acc[j].x = fmaf(yv[j].x, g, acc[j].x);
            acc[j].y = fmaf(yv[j].y, g, acc[j].y);
            acc[j].z = fmaf(yv[j].z, g, acc[j].z);
            acc[j].w = fmaf(yv[j].w, g, acc[j].w);
        }
    }
    #pragma unroll
    for (int j = 0; j < 4; ++j) {
        atomicAdd(&s_acc[col[j] + 0], acc[j].x);
        atomicAdd(&s_acc[col[j] + 1], acc[j].y);
        atomicAdd(&s_acc[col[j] + 2], acc[j].z);
        atomicAdd(&s_acc[col[j] + 3], acc[j].w);
    }
    __syncthreads();
    *(float4*)&ws[OFF_PART + (size_t)blockIdx.x * D + 4 * tid] = *(float4*)&s_acc[4 * tid];
}

__global__ __launch_bounds__(256) void k_mean(float* __restrict__ ws) {
    const int tid = threadIdx.x;
    const float* P = &ws[OFF_PART + (size_t)blockIdx.x * 16 * D];
    float4 s = make_float4(0.f, 0.f, 0.f, 0.f);
    #pragma unroll
    for (int i = 0; i < 16; ++i) {
        float4 v = ld4(&P[(size_t)i * D + 4 * tid]);
        s.x += v.x; s.y += v.y; s.z += v.z; s.w += v.w;
    }
    atomicAdd(&ws[OFF_MEAN + 4 * tid + 0], s.x);
    atomicAdd(&ws[OFF_MEAN + 4 * tid + 1], s.y);
    atomicAdd(&ws[OFF_MEAN + 4 * tid + 2], s.z);
    atomicAdd(&ws[OFF_MEAN + 4 * tid + 3], s.w);
}

__global__ __launch_bounds__(256) void k_sims(const float* __restrict__ buf,
                                              const unsigned char* __restrict__ mask,
                                              float* __restrict__ ws) {
    __shared__ float s_red[4];
    __shared__ float s_inv;
    const int tid = threadIdx.x, wave = tid >> 6, lane = tid & 63;
    float4 mv = ld4(&ws[OFF_MEAN + tid * 4]);
    float ns = mv.x * mv.x + mv.y * mv.y + mv.z * mv.z + mv.w * mv.w;
    ns = wave_red(ns);
    if (lane == 0) s_red[wave] = ns;
    __syncthreads();
    if (tid == 0) {
        float t = s_red[0] + s_red[1] + s_red[2] + s_red[3];
        s_inv = 1.0f / fmaxf(sqrtf(t), 1e-12f);
    }
    __syncthreads();
    const float inv = s_inv;
    int col[4];
    float4 mvv[4];
    #pragma unroll
    for (int j = 0; j < 4; ++j) {
        col[j] = 4 * lane + 256 * j;
        mvv[j] = ld4(&ws[OFF_MEAN + col[j]]);
    }
    const int n = blockIdx.x * 4 + wave;
    const float* br = buf + (size_t)n * D;
    float dot = 0.f, bns = 0.f;
    #pragma unroll
    for (int j = 0; j < 4; ++j) {
        float4 bv = ld4(&br[col[j]]);
        dot += bv.x * mvv[j].x + bv.y * mvv[j].y + bv.z * mvv[j].z + bv.w * mvv[j].w;
        bns += bv.x * bv.x + bv.y * bv.y + bv.z * bv.z + bv.w * bv.w;
    }
    dot = wave_red(dot);
    bns = wave_red(bns);
    if (lane == 0) {
        float sim = -1.0f;
        if (mask[n]) sim = (dot * inv) / fmaxf(sqrtf(bns), 1e-12f);
        unsigned int fb = __float_as_uint(sim);
        unsigned int mono = (fb & 0x80000000u) ? ~fb : (fb | 0x80000000u);
        unsigned long long key = ((unsigned long long)mono << 32) | (unsigned int)(~n);
        atomicMax((unsigned long long*)&ws[OFF_KEY], key);
    }
}

__global__ __launch_bounds__(256, 4) void k_passB(const float* __restrict__ x,
                                                  const float* __restrict__ buf,
                                                  const float* __restrict__ facil,
                                                  const float* __restrict__ lkb,
                                                  const float* __restrict__ lkd,
                                                  const float* __restrict__ ws,
                                                  float* __restrict__ out) {
    __shared__ float s_v[D];
    __shared__ float s_red[4];
    __shared__ float s_sc[3];
    const int tid = threadIdx.x, wave = tid >> 6, lane = tid & 63;
    const unsigned long long key = *(const unsigned long long*)&ws[OFF_KEY];
    const int idx = (int)(~(unsigned int)(key & 0xFFFFFFFFull));
    const unsigned int mono = (unsigned int)(key >> 32);
    const unsigned int fb = (mono & 0x80000000u) ? (mono ^ 0x80000000u) : ~mono;
    const float sim = __uint_as_float(fb);
    float4 vt = ld4(&buf[(size_t)idx * D + 4 * tid]);
    float bns = 0.f;
    if (!isfinite(vt.x) || !isfinite(vt.y) || !isfinite(vt.z) || !isfinite(vt.w))
        bns = __uint_as_float(0x7FC00000u);
    bns += vt.x * vt.x + vt.y * vt.y + vt.z * vt.z + vt.w * vt.w;
    bns = wave_red(bns);
    if (lane == 0) s_red[wave] = bns;
    __syncthreads();
    if (tid == 0) {
        float t = s_red[0] + s_red[1] + s_red[2] + s_red[3];
        int valid = (t >= 1e-12f) ? 1 : 0;
        float sim_val = fminf(fmaxf(sim, 0.0f), 1.0f);
        float fl = facil[idx] * ((sim_val > 0.88f) ? 2.0f : 1.0f);
        float mod = (fl - 1.0f) * sim_val;
        float kb = fminf(fmaxf(__expf(lkb[0]), 0.01f), 4.0f);
        float kd = fminf(fmaxf(__expf(lkd[0]), 0.01f), 0.9f);
        float boost = 1.0f + kb * mod;
        float damp = fmaxf(0.01f, 1.0f - kd * mod);
        s_sc[0] = valid ? damp : 1.0f;
        s_sc[1] = valid ? (boost - damp) : 0.0f;
        s_sc[2] = (float)valid;
    }
    __syncthreads();
    const float dampe = s_sc[0], coef = s_sc[1];
    if (s_sc[2] == 0.0f) vt = make_float4(0.f, 0.f, 0.f, 0.f);
    *(float4*)&s_v[4 * tid] = vt;
    __syncthreads();
    int col[4];
    #pragma unroll
    for (int j = 0; j < 4; ++j) col[j] = 4 * lane + 256 * j;
    const int r0 = (blockIdx.x * 4 + wave) * 2;
    for (int r = r0; r < r0 + 2; ++r) {
        const float* xr = x + (size_t)r * D;
        const float g = ws[OFF_GATE + r];
        float4 y1[4], vvv[4];
        float proj = 0.f;
        #pragma unroll
        for (int j = 0; j < 4; ++j) {
            float4 xv = ld4(&xr[col[j]]);
            vvv[j] = *(const float4*)&s_v[col[j]];
            y1[j] = gelu4(xv);
            y1[j].x *= g; y1[j].y *= g; y1[j].z *= g; y1[j].w *= g;
            proj = fmaf(y1[j].x, vvv[j].x, proj);
            proj = fmaf(y1[j].y, vvv[j].y, proj);
            proj = fmaf(y1[j].z, vvv[j].z, proj);
            proj = fmaf(y1[j].w, vvv[j].w, proj);
        }
        proj = wave_red(proj);
        const float pc = proj * coef;
        float* orow = out + (size_t)r * D;
        #pragma unroll
        for (int j = 0; j < 4; ++j) {
            float4 o;
            o.x = fmaf(y1[j].x, dampe, pc * vvv[j].x);
            o.y = fmaf(y1[j].y, dampe, pc * vvv[j].y);
            o.z = fmaf(y1[j].z, dampe, pc * vvv[j].z);
            o.w = fmaf(y1[j].w, dampe, pc * vvv[j].w);
            *(float4*)&orow[col[j]] = o;
        }
    }
}

extern "C" void kernel_launch(void* const* d_in, const int* in_sizes, int n_in,
                              void* d_out, int out_size, void* d_ws, size_t ws_size,
                              hipStream_t stream) {
    const float* x      = (const float*)d_in[0];
    const float* lti    = (const float*)d_in[1];
    const float* lto    = (const float*)d_in[2];
    const float* lai    = (const float*)d_in[3];
    const float* lao    = (const float*)d_in[4];
    const float* lkb    = (const float*)d_in[5];
    const float* lkd    = (const float*)d_in[6];
    const float* ema_x  = (const float*)d_in[7];
    const float* ema_x2 = (const float*)d_in[8];
    const float* ema_y  = (const float*)d_in[9];
    const float* ema_y2 = (const float*)d_in[10];
    const float* buf    = (const float*)d_in[11];
    const float* facil  = (const float*)d_in[12];
    const unsigned char* mask = (const unsigned char*)d_in[13];
    float* ws  = (float*)d_ws;
    float* out = (float*)d_out;

    void* args[] = {
        (void*)&x,
        (void*)&ema_x, (void*)&ema_x2, (void*)&ema_y, (void*)&ema_y2,
        (void*)&lti, (void*)&lto, (void*)&lai, (void*)&lao,
        (void*)&buf, (void*)&facil, (void*)&lkb, (void*)&lkd,
        (void*)&mask, (void*)&ws, (void*)&out,
    };
    hipError_t err = hipLaunchCooperativeKernel((void*)k_fused, dim3(NBLK), dim3(256),
                                                args, 0, stream);
    if (err != hipSuccess) {
        // verified multi-kernel fallback (R5 path)
        int NP;
        if      (ws_size >= ((size_t)OFF_PART + 2048u * D) * 4) NP = 2048;
        else if (ws_size >= ((size_t)OFF_PART + 1024u * D) * 4) NP = 1024;
        else                                                    NP = 512;
        hipLaunchKernelGGL(k_init, dim3(1), dim3(1024), 0, stream,
                           ema_x, ema_x2, ema_y, ema_y2, lti, lto, lai, lao, ws);
        if (NP == 2048)
            hipLaunchKernelGGL(k_passA<2>, dim3(2048), dim3(256), 0, stream, x, ws);
        else if (NP == 1024)
            hipLaunchKernelGGL(k_passA<4>, dim3(1024), dim3(256), 0, stream, x, ws);
        else
            hipLaunchKernelGGL(k_passA<8>, dim3(512), dim3(256), 0, stream, x, ws);
        hipLaunchKernelGGL(k_mean, dim3(NP / 16), dim3(256), 0, stream, ws);
        hipLaunchKernelGGL(k_sims, dim3(128), dim3(256), 0, stream, buf, mask, ws);
        hipLaunchKernelGGL(k_passB, dim3(2048), dim3(256), 0, stream,
                           x, buf, facil, lkb, lkd, ws, out);
    }
}

// Round 8
// 190.595 us; speedup vs baseline: 2.6882x; 2.6882x over previous
//
#include <hip/hip_runtime.h>
#include <math.h>

#define D 1024
#define NROWS 16384
#define NBUF 512
#define NBLKA 512   // passA/passB grid: empirically fastest per-pass size

// ws layout (float indices)
#define OFF_MEAN 0      // 1024 floats: column sums of y1
#define OFF_KEY  1024   // unsigned long long at byte 4096
#define OFF_GATE 2048   // 16384 floats
#define OFF_PART 20480  // NBLKA x 1024 floats
#define ZERO_BYTES 4112 // MEAN + KEY

typedef float nfloat4 __attribute__((ext_vector_type(4)));

__device__ __forceinline__ float4 ld4(const float* p) { return *(const float4*)p; }
__device__ __forceinline__ void st4_nt(float* p, float4 v) {
    nfloat4 nv = { v.x, v.y, v.z, v.w };
    __builtin_nontemporal_store(nv, (nfloat4*)p);
}

__device__ __forceinline__ float wave_red(float v) {
    #pragma unroll
    for (int off = 32; off > 0; off >>= 1) v += __shfl_xor(v, off, 64);
    return v;
}

__device__ __forceinline__ float gelu_f(float x) {
    float x2 = x * x;
    float t1 = fmaf(0.044715f, x2, 1.0f);
    float u2 = (1.5957691216057308f * x) * t1;
    float e  = __expf(u2);
    float r  = __builtin_amdgcn_rcpf(e + 1.0f);
    return fmaf(-x, r, x);
}

__device__ __forceinline__ float4 gelu4(float4 x) {
    float4 y;
    y.x = gelu_f(x.x); y.y = gelu_f(x.y); y.z = gelu_f(x.z); y.w = gelu_f(x.w);
    return y;
}

// ---------------- K1: pass A — gates + per-block column partials --------------
// 512 blocks x 256; 8 rows/wave processed as 4 pairs (8 loads in flight,
// 4 interleaved reduction chains). Stats folded per block into LDS.
__global__ __launch_bounds__(256, 4) void k_passA(const float* __restrict__ x,
                                                  const float* __restrict__ ema_x,
                                                  const float* __restrict__ ema_x2,
                                                  const float* __restrict__ ema_y,
                                                  const float* __restrict__ ema_y2,
                                                  const float* __restrict__ lti,
                                                  const float* __restrict__ lto,
                                                  const float* __restrict__ lai,
                                                  const float* __restrict__ lao,
                                                  float* __restrict__ ws) {
    __shared__ float s_stat[4096];   // ax | bx | ay | by
    __shared__ float s_acc[D];
    const int tid = threadIdx.x, wave = tid >> 6, lane = tid & 63;

    for (int i = tid; i < 1024; i += 256) {
        float mx = ema_x[i];
        float vx = fmaxf(ema_x2[i] - mx * mx, 0.0f);
        float ax = 1.0f / (sqrtf(vx) + 1e-5f);
        s_stat[i]        = ax;
        s_stat[1024 + i] = mx * ax;
        float my = ema_y[i];
        float vy = fmaxf(ema_y2[i] - my * my, 0.0f);
        float ay = 1.0f / (sqrtf(vy) + 1e-5f);
        s_stat[2048 + i] = ay;
        s_stat[3072 + i] = my * ay;
        s_acc[i] = 0.0f;
    }
    __syncthreads();

    const float tau_in = __expf(lti[0]), tau_out = __expf(lto[0]);
    const float a_in  = 1.0f / (1.0f + __expf(-lai[0]));
    const float a_out = 1.0f / (1.0f + __expf(-lao[0]));

    int col[4];
    #pragma unroll
    for (int j = 0; j < 4; ++j) col[j] = 4 * lane + 256 * j;

    float4 acc[4];
    #pragma unroll
    for (int j = 0; j < 4; ++j) acc[j] = make_float4(0.f, 0.f, 0.f, 0.f);

    const int r0 = (blockIdx.x * 4 + wave) * 8;   // 8 rows per wave
    #pragma unroll
    for (int k = 0; k < 4; ++k) {
        const int rA = r0 + 2 * k, rB = rA + 1;
        const float* pA = x + (size_t)rA * D;
        const float* pB = x + (size_t)rB * D;
        float4 xA[4], xB[4];
        #pragma unroll
        for (int j = 0; j < 4; ++j) { xA[j] = ld4(&pA[col[j]]); xB[j] = ld4(&pB[col[j]]); }

        float4 yA[4], yB[4];
        float zinA = 0.f, zinB = 0.f, zoutA = 0.f, zoutB = 0.f;
        #pragma unroll
        for (int j = 0; j < 4; ++j) {
            float4 a  = *(const float4*)&s_stat[col[j]];
            float4 bb = *(const float4*)&s_stat[1024 + col[j]];
            float d;
            d = fmaf(xA[j].x, a.x, -bb.x); zinA = fmaf(d, d, zinA);
            d = fmaf(xA[j].y, a.y, -bb.y); zinA = fmaf(d, d, zinA);
            d = fmaf(xA[j].z, a.z, -bb.z); zinA = fmaf(d, d, zinA);
            d = fmaf(xA[j].w, a.w, -bb.w); zinA = fmaf(d, d, zinA);
            d = fmaf(xB[j].x, a.x, -bb.x); zinB = fmaf(d, d, zinB);
            d = fmaf(xB[j].y, a.y, -bb.y); zinB = fmaf(d, d, zinB);
            d = fmaf(xB[j].z, a.z, -bb.z); zinB = fmaf(d, d, zinB);
            d = fmaf(xB[j].w, a.w, -bb.w); zinB = fmaf(d, d, zinB);
            yA[j] = gelu4(xA[j]);
            yB[j] = gelu4(xB[j]);
            float4 ay = *(const float4*)&s_stat[2048 + col[j]];
            float4 by = *(const float4*)&s_stat[3072 + col[j]];
            d = fmaf(yA[j].x, ay.x, -by.x); zoutA = fmaf(d, d, zoutA);
            d = fmaf(yA[j].y, ay.y, -by.y); zoutA = fmaf(d, d, zoutA);
            d = fmaf(yA[j].z, ay.z, -by.z); zoutA = fmaf(d, d, zoutA);
            d = fmaf(yA[j].w, ay.w, -by.w); zoutA = fmaf(d, d, zoutA);
            d = fmaf(yB[j].x, ay.x, -by.x); zoutB = fmaf(d, d, zoutB);
            d = fmaf(yB[j].y, ay.y, -by.y); zoutB = fmaf(d, d, zoutB);
            d = fmaf(yB[j].z, ay.z, -by.z); zoutB = fmaf(d, d, zoutB);
            d = fmaf(yB[j].w, ay.w, -by.w); zoutB = fmaf(d, d, zoutB);
        }
        zinA  = wave_red(zinA)  * (1.0f / D);
        zinB  = wave_red(zinB)  * (1.0f / D);
        zoutA = wave_red(zoutA) * (1.0f / D);
        zoutB = wave_red(zoutB) * (1.0f / D);
        float gA = ((1.0f - a_in)  + a_in  * __expf(-tau_in  * zinA)) *
                   ((1.0f - a_out) + a_out * __expf(-tau_out * zoutA));
        float gB = ((1.0f - a_in)  + a_in  * __expf(-tau_in  * zinB)) *
                   ((1.0f - a_out) + a_out * __expf(-tau_out * zoutB));
        if (lane == 0) { ws[OFF_GATE + rA] = gA; ws[OFF_GATE + rB] = gB; }
        #pragma unroll
        for (int j = 0; j < 4; ++j) {
            acc[j].x = fmaf(yA[j].x, gA, fmaf(yB[j].x, gB, acc[j].x));
            acc[j].y = fmaf(yA[j].y, gA, fmaf(yB[j].y, gB, acc[j].y));
            acc[j].z = fmaf(yA[j].z, gA, fmaf(yB[j].z, gB, acc[j].z));
            acc[j].w = fmaf(yA[j].w, gA, fmaf(yB[j].w, gB, acc[j].w));
        }
    }
    #pragma unroll
    for (int j = 0; j < 4; ++j) {
        atomicAdd(&s_acc[col[j] + 0], acc[j].x);
        atomicAdd(&s_acc[col[j] + 1], acc[j].y);
        atomicAdd(&s_acc[col[j] + 2], acc[j].z);
        atomicAdd(&s_acc[col[j] + 3], acc[j].w);
    }
    __syncthreads();
    *(float4*)&ws[OFF_PART + (size_t)blockIdx.x * D + 4 * tid] = *(float4*)&s_acc[4 * tid];
}

// ---------------- K2: reduce 512 partials -> column sums ----------------------
// 32 blocks x 256; block b sums partial rows [16b, 16b+16); 32 atomics/address.
__global__ __launch_bounds__(256) void k_mean(float* __restrict__ ws) {
    const int tid = threadIdx.x;
    const float* P = &ws[OFF_PART + (size_t)blockIdx.x * 16 * D];
    float4 s = make_float4(0.f, 0.f, 0.f, 0.f);
    #pragma unroll
    for (int i = 0; i < 16; ++i) {
        float4 v = ld4(&P[(size_t)i * D + 4 * tid]);
        s.x += v.x; s.y += v.y; s.z += v.z; s.w += v.w;
    }
    atomicAdd(&ws[OFF_MEAN + 4 * tid + 0], s.x);
    atomicAdd(&ws[OFF_MEAN + 4 * tid + 1], s.y);
    atomicAdd(&ws[OFF_MEAN + 4 * tid + 2], s.z);
    atomicAdd(&ws[OFF_MEAN + 4 * tid + 3], s.w);
}

// ---------------- K3: sims over buf + argmax via atomicMax key ----------------
// 1/NROWS cancels in normalization, so column SUMS suffice.
__global__ __launch_bounds__(256) void k_sims(const float* __restrict__ buf,
                                              const unsigned char* __restrict__ mask,
                                              float* __restrict__ ws) {
    __shared__ float s_red[4];
    __shared__ float s_inv;
    const int tid = threadIdx.x, wave = tid >> 6, lane = tid & 63;

    float4 mv = ld4(&ws[OFF_MEAN + 4 * tid]);
    float ns = mv.x * mv.x + mv.y * mv.y + mv.z * mv.z + mv.w * mv.w;
    ns = wave_red(ns);
    if (lane == 0) s_red[wave] = ns;
    __syncthreads();
    if (tid == 0) {
        float t = s_red[0] + s_red[1] + s_red[2] + s_red[3];
        s_inv = 1.0f / fmaxf(sqrtf(t), 1e-12f);
    }
    __syncthreads();
    const float inv = s_inv;

    int col[4];
    float4 mvv[4];
    #pragma unroll
    for (int j = 0; j < 4; ++j) {
        col[j] = 4 * lane + 256 * j;
        mvv[j] = ld4(&ws[OFF_MEAN + col[j]]);
    }
    const int n = blockIdx.x * 4 + wave;   // 128 blocks x 4 waves = 512 rows
    const float* br = buf + (size_t)n * D;
    float dot = 0.f, bns = 0.f;
    #pragma unroll
    for (int j = 0; j < 4; ++j) {
        float4 bv = ld4(&br[col[j]]);
        dot = fmaf(bv.x, mvv[j].x, dot); dot = fmaf(bv.y, mvv[j].y, dot);
        dot = fmaf(bv.z, mvv[j].z, dot); dot = fmaf(bv.w, mvv[j].w, dot);
        bns = fmaf(bv.x, bv.x, bns); bns = fmaf(bv.y, bv.y, bns);
        bns = fmaf(bv.z, bv.z, bns); bns = fmaf(bv.w, bv.w, bns);
    }
    dot = wave_red(dot);
    bns = wave_red(bns);
    if (lane == 0) {
        float sim = -1.0f;
        if (mask[n]) sim = (dot * inv) / fmaxf(sqrtf(bns), 1e-12f);
        unsigned int fb = __float_as_uint(sim);
        unsigned int mono = (fb & 0x80000000u) ? ~fb : (fb | 0x80000000u);
        // ~n in low bits => ties resolve to smallest index (jnp.argmax)
        unsigned long long key = ((unsigned long long)mono << 32) | (unsigned int)(~n);
        atomicMax((unsigned long long*)&ws[OFF_KEY], key);
    }
}

// ---------------- K4: pass B — decode winner, project, write out --------------
__global__ __launch_bounds__(256, 4) void k_passB(const float* __restrict__ x,
                                                  const float* __restrict__ buf,
                                                  const float* __restrict__ facil,
                                                  const float* __restrict__ lkb,
                                                  const float* __restrict__ lkd,
                                                  const float* __restrict__ ws,
                                                  float* __restrict__ out) {
    __shared__ float s_v[D];
    __shared__ float s_red[4];
    __shared__ float s_sc[3];   // dampe, coef, valid
    const int tid = threadIdx.x, wave = tid >> 6, lane = tid & 63;

    const unsigned long long key = *(const unsigned long long*)&ws[OFF_KEY];
    const int idx = (int)(~(unsigned int)(key & 0xFFFFFFFFull));
    const unsigned int mono = (unsigned int)(key >> 32);
    const unsigned int fb = (mono & 0x80000000u) ? (mono ^ 0x80000000u) : ~mono;
    const float sim = __uint_as_float(fb);

    float4 vt = ld4(&buf[(size_t)idx * D + 4 * tid]);
    float bns = 0.f;
    if (!isfinite(vt.x) || !isfinite(vt.y) || !isfinite(vt.z) || !isfinite(vt.w))
        bns = __uint_as_float(0x7FC00000u);   // NaN poison -> valid=0
    bns += vt.x * vt.x + vt.y * vt.y + vt.z * vt.z + vt.w * vt.w;
    bns = wave_red(bns);
    if (lane == 0) s_red[wave] = bns;
    __syncthreads();
    if (tid == 0) {
        float t = s_red[0] + s_red[1] + s_red[2] + s_red[3];
        int valid = (t >= 1e-12f) ? 1 : 0;    // NaN compares false
        float sim_val = fminf(fmaxf(sim, 0.0f), 1.0f);
        float fl = facil[idx] * ((sim_val > 0.88f) ? 2.0f : 1.0f);
        float mod = (fl - 1.0f) * sim_val;
        float kb = fminf(fmaxf(__expf(lkb[0]), 0.01f), 4.0f);
        float kd = fminf(fmaxf(__expf(lkd[0]), 0.01f), 0.9f);
        float boost = 1.0f + kb * mod;
        float damp = fmaxf(0.01f, 1.0f - kd * mod);
        s_sc[0] = valid ? damp : 1.0f;
        s_sc[1] = valid ? (boost - damp) : 0.0f;
        s_sc[2] = (float)valid;
    }
    __syncthreads();
    const float dampe = s_sc[0], coef = s_sc[1];
    if (s_sc[2] == 0.0f) vt = make_float4(0.f, 0.f, 0.f, 0.f);
    *(float4*)&s_v[4 * tid] = vt;
    __syncthreads();

    int col[4];
    float4 vv[4];
    #pragma unroll
    for (int j = 0; j < 4; ++j) {
        col[j] = 4 * lane + 256 * j;
        vv[j] = *(const float4*)&s_v[col[j]];
    }

    const int r0 = (blockIdx.x * 4 + wave) * 8;   // 512 blocks, 8 rows/wave
    #pragma unroll
    for (int k = 0; k < 4; ++k) {
        const int rA = r0 + 2 * k, rB = rA + 1;
        const float gA = ws[OFF_GATE + rA], gB = ws[OFF_GATE + rB];
        const float* pA = x + (size_t)rA * D;
        const float* pB = x + (size_t)rB * D;
        float4 xA[4], xB[4];
        #pragma unroll
        for (int j = 0; j < 4; ++j) { xA[j] = ld4(&pA[col[j]]); xB[j] = ld4(&pB[col[j]]); }
        float4 yA[4], yB[4];
        float projA = 0.f, projB = 0.f;
        #pragma unroll
        for (int j = 0; j < 4; ++j) {
            yA[j] = gelu4(xA[j]);
            yA[j].x *= gA; yA[j].y *= gA; yA[j].z *= gA; yA[j].w *= gA;
            yB[j] = gelu4(xB[j]);
            yB[j].x *= gB; yB[j].y *= gB; yB[j].z *= gB; yB[j].w *= gB;
            projA = fmaf(yA[j].x, vv[j].x, projA); projA = fmaf(yA[j].y, vv[j].y, projA);
            projA = fmaf(yA[j].z, vv[j].z, projA); projA = fmaf(yA[j].w, vv[j].w, projA);
            projB = fmaf(yB[j].x, vv[j].x, projB); projB = fmaf(yB[j].y, vv[j].y, projB);
            projB = fmaf(yB[j].z, vv[j].z, projB); projB = fmaf(yB[j].w, vv[j].w, projB);
        }
        projA = wave_red(projA);
        projB = wave_red(projB);
        const float pcA = projA * coef, pcB = projB * coef;
        float* oA = out + (size_t)rA * D;
        float* oB = out + (size_t)rB * D;
        #pragma unroll
        for (int j = 0; j < 4; ++j) {
            float4 o;
            o.x = fmaf(yA[j].x, dampe, pcA * vv[j].x);
            o.y = fmaf(yA[j].y, dampe, pcA * vv[j].y);
            o.z = fmaf(yA[j].z, dampe, pcA * vv[j].z);
            o.w = fmaf(yA[j].w, dampe, pcA * vv[j].w);
            st4_nt(&oA[col[j]], o);
            o.x = fmaf(yB[j].x, dampe, pcB * vv[j].x);
            o.y = fmaf(yB[j].y, dampe, pcB * vv[j].y);
            o.z = fmaf(yB[j].z, dampe, pcB * vv[j].z);
            o.w = fmaf(yB[j].w, dampe, pcB * vv[j].w);
            st4_nt(&oB[col[j]], o);
        }
    }
}

extern "C" void kernel_launch(void* const* d_in, const int* in_sizes, int n_in,
                              void* d_out, int out_size, void* d_ws, size_t ws_size,
                              hipStream_t stream) {
    const float* x      = (const float*)d_in[0];
    const float* lti    = (const float*)d_in[1];
    const float* lto    = (const float*)d_in[2];
    const float* lai    = (const float*)d_in[3];
    const float* lao    = (const float*)d_in[4];
    const float* lkb    = (const float*)d_in[5];
    const float* lkd    = (const float*)d_in[6];
    const float* ema_x  = (const float*)d_in[7];
    const float* ema_x2 = (const float*)d_in[8];
    const float* ema_y  = (const float*)d_in[9];
    const float* ema_y2 = (const float*)d_in[10];
    const float* buf    = (const float*)d_in[11];
    const float* facil  = (const float*)d_in[12];
    const unsigned char* mask = (const unsigned char*)d_in[13];
    float* ws  = (float*)d_ws;
    float* out = (float*)d_out;

    (void)hipMemsetAsync(d_ws, 0, ZERO_BYTES, stream);
    hipLaunchKernelGGL(k_passA, dim3(NBLKA), dim3(256), 0, stream,
                       x, ema_x, ema_x2, ema_y, ema_y2, lti, lto, lai, lao, ws);
    hipLaunchKernelGGL(k_mean,  dim3(NBLKA / 16), dim3(256), 0, stream, ws);
    hipLaunchKernelGGL(k_sims,  dim3(128), dim3(256), 0, stream, buf, mask, ws);
    hipLaunchKernelGGL(k_passB, dim3(NBLKA), dim3(256), 0, stream,
                       x, buf, facil, lkb, lkd, ws, out);
}